// Round 5
// baseline (11596.181 us; speedup 1.0000x reference)
//
#include <hip/hip_runtime.h>
#include <cmath>

using u16 = unsigned short;
using u32 = unsigned int;
using bf16x8 = __attribute__((ext_vector_type(8))) __bf16;
using f32x4 = __attribute__((ext_vector_type(4))) float;

__device__ __forceinline__ u16 f2bf(float f) {
  union { float f; u32 i; } x; x.f = f;
  u32 r = x.i + 0x7FFFu + ((x.i >> 16) & 1u);
  return (u16)(r >> 16);
}
__device__ __forceinline__ float bf2f(u16 u) {
  union { u32 i; float f; } x; x.i = (u32)u << 16; return x.f;
}
__device__ __forceinline__ float fast_tanh(float x) {
  float e = __expf(2.0f * x);
  return 1.0f - 2.0f / (e + 1.0f);
}

// ---------------- fp32 -> bf16 bulk convert ----------------
__global__ void cvt_bf16(const float* __restrict__ src, u16* __restrict__ dst, int n) {
  int i = (blockIdx.x * 256 + threadIdx.x) * 8;
  if (i + 8 <= n) {
    float4 a = *(const float4*)(src + i), b = *(const float4*)(src + i + 4);
    u16 t[8] = {f2bf(a.x), f2bf(a.y), f2bf(a.z), f2bf(a.w),
                f2bf(b.x), f2bf(b.y), f2bf(b.z), f2bf(b.w)};
    *(uint4*)(dst + i) = *(uint4*)t;
  }
}

// ---------------- boxesT[i][b][f] = tanh(inp[b][i]@Wb^T + bb) ----------------
__global__ __launch_bounds__(256) void box_allT(const float* __restrict__ inp,
    const float* __restrict__ Wb, const float* __restrict__ bb, u16* __restrict__ boxesT) {
  int b = blockIdx.x, t = threadIdx.x;
  __shared__ float sin_[64][12];
  for (int idx = t; idx < 768; idx += 256) sin_[idx / 12][idx % 12] = inp[(long)b * 768 + idx];
  int f0 = (t & 127) * 4, hf = t >> 7;
  float w[4][12], bz[4];
#pragma unroll
  for (int r = 0; r < 4; ++r) {
    bz[r] = bb[f0 + r];
#pragma unroll
    for (int q = 0; q < 12; ++q) w[r][q] = Wb[(f0 + r) * 12 + q];
  }
  __syncthreads();
  for (int i = hf; i < 64; i += 2) {
    float a[4] = {bz[0], bz[1], bz[2], bz[3]};
#pragma unroll
    for (int q = 0; q < 12; ++q) {
      float x = sin_[i][q];
#pragma unroll
      for (int r = 0; r < 4; ++r) a[r] += x * w[r][q];
    }
    u16 p[4];
#pragma unroll
    for (int r = 0; r < 4; ++r) p[r] = f2bf(fast_tanh(a[r]));
    *(uint2*)&boxesT[((long)i * 2048 + b) * 512 + f0] = *(uint2*)p;
  }
}

// ---------------- whole sequential chain: 63 left-steps + 16 sym-steps ----------------
// 128 blocks x 16 rows. acc/h/box in LDS; weight B-frags streamed from L2.
// Left (chain): h = tanh(acc@Wl^T + box_bp@Wr^T + bl)     [K=512 + K=512]
// Left (sym):   h = tanh(acc@Sl^T + sbl + sym@Sr^T + sbr) [K=512 + fp32 K=8]
// Proj:         acc = tanh(h@{Ws|Ss}^T + {bs|sbs})        [K=1024]
__global__ __launch_bounds__(256, 1) void chain_kernel(
    const u16* __restrict__ boxesT,
    const u16* __restrict__ Wl, const u16* __restrict__ Wr, const u16* __restrict__ Ws,
    const u16* __restrict__ Sl, const u16* __restrict__ Ss,
    const float* __restrict__ bl, const float* __restrict__ bs,
    const float* __restrict__ sbl, const float* __restrict__ sbr,
    const float* __restrict__ sbs, const float* __restrict__ SrF,
    const float* __restrict__ sym, float* __restrict__ outF) {
  __shared__ u16 sA[16][520];   // acc  (A operand, K=512), +8 pad: 2-way banks (free)
  __shared__ u16 sB[16][520];   // box  (A operand, K=512)
  __shared__ u16 sH[16][1032];  // h    (A operand, K=1024)
  __shared__ float sSym[16][8];

  const int tid = threadIdx.x, lane = tid & 63, w = tid >> 6;
  const int q = lane >> 4, l16 = lane & 15;
  const int m0 = blockIdx.x * 16;
  const int brow = tid >> 4, bcol = (tid & 15) * 32;

  // init acc <- boxesT[63]
  {
    const u16* src = boxesT + ((long)63 * 2048 + m0 + brow) * 512 + bcol;
#pragma unroll
    for (int v = 0; v < 4; ++v)
      *(uint4*)&sA[brow][bcol + v * 8] = *(const uint4*)(src + v * 8);
  }
  __syncthreads();

  for (int t = 0; t < 79; ++t) {
    const bool symPhase = (t >= 63);
    const int bp = 62 - t;

    // issue box tile loads early (latency covered by pass-1 MFMA)
    uint4 boxv[4];
    if (!symPhase) {
      const u16* bsrc = boxesT + ((long)bp * 2048 + m0 + brow) * 512 + bcol;
#pragma unroll
      for (int v = 0; v < 4; ++v) boxv[v] = *(const uint4*)(bsrc + v * 8);
    } else {
      int symp = 15 - (t - 63);
      if (tid < 128) sSym[tid >> 3][tid & 7] =
          sym[((long)(m0 + (tid >> 3)) * 16 + symp) * 8 + (tid & 7)];
      __syncthreads();
    }

    // ---- LEFT pass 1: acc @ {Wl|Sl}^T ----
    const u16* WL = symPhase ? Sl : Wl;
    bf16x8 Af[16];
#pragma unroll
    for (int s = 0; s < 16; ++s) Af[s] = *(const bf16x8*)&sA[l16][s * 32 + q * 8];
    f32x4 C0[8], C1[8];
#pragma unroll
    for (int np = 0; np < 8; ++np) {
      const int n0 = w * 256 + np * 32;
      C0[np] = (f32x4){0.f, 0.f, 0.f, 0.f};
      C1[np] = (f32x4){0.f, 0.f, 0.f, 0.f};
      const u16* w0 = WL + (long)(n0 + l16) * 512 + q * 8;
      const u16* w1 = w0 + 16 * 512;
#pragma unroll 8
      for (int s = 0; s < 16; ++s) {
        bf16x8 b0 = *(const bf16x8*)(w0 + s * 32);
        bf16x8 b1 = *(const bf16x8*)(w1 + s * 32);
        C0[np] = __builtin_amdgcn_mfma_f32_16x16x32_bf16(Af[s], b0, C0[np], 0, 0, 0);
        C1[np] = __builtin_amdgcn_mfma_f32_16x16x32_bf16(Af[s], b1, C1[np], 0, 0, 0);
      }
    }
    // ---- LEFT pass 2 (chain only): + box_bp @ Wr^T ----
    if (!symPhase) {
#pragma unroll
      for (int v = 0; v < 4; ++v) *(uint4*)&sB[brow][bcol + v * 8] = boxv[v];
      __syncthreads();
      bf16x8 Ab[16];
#pragma unroll
      for (int s = 0; s < 16; ++s) Ab[s] = *(const bf16x8*)&sB[l16][s * 32 + q * 8];
#pragma unroll
      for (int np = 0; np < 8; ++np) {
        const int n0 = w * 256 + np * 32;
        const u16* w0 = Wr + (long)(n0 + l16) * 512 + q * 8;
        const u16* w1 = w0 + 16 * 512;
#pragma unroll 8
        for (int s = 0; s < 16; ++s) {
          bf16x8 b0 = *(const bf16x8*)(w0 + s * 32);
          bf16x8 b1 = *(const bf16x8*)(w1 + s * 32);
          C0[np] = __builtin_amdgcn_mfma_f32_16x16x32_bf16(Ab[s], b0, C0[np], 0, 0, 0);
          C1[np] = __builtin_amdgcn_mfma_f32_16x16x32_bf16(Ab[s], b1, C1[np], 0, 0, 0);
        }
      }
    }
    // ---- LEFT epilogue: bias (+ sym@Sr^T), tanh, write h ----
    float symv[4][8];
    if (symPhase) {
#pragma unroll
      for (int r = 0; r < 4; ++r)
#pragma unroll
        for (int k = 0; k < 8; ++k) symv[r][k] = sSym[q * 4 + r][k];
    }
#pragma unroll
    for (int np = 0; np < 8; ++np) {
      const int n0 = w * 256 + np * 32;
      const int n0b = n0 + l16, n1b = n0 + 16 + l16;
      float bn0, bn1, sr0[8], sr1[8];
      if (!symPhase) { bn0 = bl[n0b]; bn1 = bl[n1b]; }
      else {
        bn0 = sbl[n0b] + sbr[n0b]; bn1 = sbl[n1b] + sbr[n1b];
        *(float4*)&sr0[0] = *(const float4*)&SrF[(long)n0b * 8];
        *(float4*)&sr0[4] = *(const float4*)&SrF[(long)n0b * 8 + 4];
        *(float4*)&sr1[0] = *(const float4*)&SrF[(long)n1b * 8];
        *(float4*)&sr1[4] = *(const float4*)&SrF[(long)n1b * 8 + 4];
      }
#pragma unroll
      for (int r = 0; r < 4; ++r) {
        int m = q * 4 + r;
        float v0 = C0[np][r] + bn0;
        float v1 = C1[np][r] + bn1;
        if (symPhase) {
#pragma unroll
          for (int k = 0; k < 8; ++k) { v0 += symv[r][k] * sr0[k]; v1 += symv[r][k] * sr1[k]; }
        }
        sH[m][n0b] = f2bf(fast_tanh(v0));
        sH[m][n1b] = f2bf(fast_tanh(v1));
      }
    }
    __syncthreads();

    // ---- PROJ: acc' = tanh(h @ {Ws|Ss}^T + bias) ----
    const u16* WP = symPhase ? Ss : Ws;
    const float* b2 = symPhase ? sbs : bs;
    bf16x8 Hf[32];
#pragma unroll
    for (int s = 0; s < 32; ++s) Hf[s] = *(const bf16x8*)&sH[l16][s * 32 + q * 8];
    const bool last = (t == 78);
#pragma unroll
    for (int fp = 0; fp < 4; ++fp) {
      const int f0 = w * 128 + fp * 32;
      f32x4 D0 = {0.f, 0.f, 0.f, 0.f}, D1 = {0.f, 0.f, 0.f, 0.f};
      const u16* w0 = WP + (long)(f0 + l16) * 1024 + q * 8;
      const u16* w1 = w0 + 16 * 1024;
#pragma unroll 8
      for (int s = 0; s < 32; ++s) {
        bf16x8 b0 = *(const bf16x8*)(w0 + s * 32);
        bf16x8 b1 = *(const bf16x8*)(w1 + s * 32);
        D0 = __builtin_amdgcn_mfma_f32_16x16x32_bf16(Hf[s], b0, D0, 0, 0, 0);
        D1 = __builtin_amdgcn_mfma_f32_16x16x32_bf16(Hf[s], b1, D1, 0, 0, 0);
      }
      const int f0b = f0 + l16, f1b = f0 + 16 + l16;
      float bn0 = b2[f0b], bn1 = b2[f1b];
#pragma unroll
      for (int r = 0; r < 4; ++r) {
        int m = q * 4 + r;
        float a0 = fast_tanh(D0[r] + bn0);
        float a1 = fast_tanh(D1[r] + bn1);
        sA[m][f0b] = f2bf(a0);
        sA[m][f1b] = f2bf(a1);
        if (last) {
          outF[(long)(m0 + m) * 512 + f0b] = a0;
          outF[(long)(m0 + m) * 512 + f1b] = a1;
        }
      }
    }
    __syncthreads();
  }
}

// ================= fallback kernels (small-ws path, proven round-3 logic) =================
__global__ __launch_bounds__(256) void box_all_v2(const float* __restrict__ inp,
    const float* __restrict__ Wb, const float* __restrict__ bb, u16* __restrict__ boxes) {
  int b = blockIdx.x, t = threadIdx.x;
  __shared__ float sin_[64][12];
  for (int idx = t; idx < 768; idx += 256) sin_[idx / 12][idx % 12] = inp[(long)b * 768 + idx];
  const int f0 = t * 2;
  float w0[12], w1[12];
#pragma unroll
  for (int q = 0; q < 12; ++q) { w0[q] = Wb[f0 * 12 + q]; w1[q] = Wb[(f0 + 1) * 12 + q]; }
  float b0 = bb[f0], b1 = bb[f0 + 1];
  __syncthreads();
  for (int i = 0; i < 64; ++i) {
    float a0 = b0, a1 = b1;
#pragma unroll
    for (int q = 0; q < 12; ++q) { float x = sin_[i][q]; a0 += x * w0[q]; a1 += x * w1[q]; }
    u32 pk = (u32)f2bf(fast_tanh(a0)) | ((u32)f2bf(fast_tanh(a1)) << 16);
    *(u32*)&boxes[(((long)b * 64 + i) * 512) + f0] = pk;
  }
}

__global__ __launch_bounds__(256) void gemm64(
    const u16* __restrict__ A1, int lda1,
    const u16* __restrict__ W1b, const float* __restrict__ W1f, int K1,
    const u16* __restrict__ A2, int lda2,
    const u16* __restrict__ W2b, const float* __restrict__ W2f, int K2,
    const float* __restrict__ bias,
    const float* __restrict__ symS, const float* __restrict__ Srw, const float* __restrict__ sbr,
    int doTanh, int outMode,
    u16* __restrict__ Cb, float* __restrict__ Cf, int N) {
  __shared__ u16 As[64][72];
  __shared__ u16 Bs[64][72];
  const int tid = threadIdx.x;
  const int lane = tid & 63, w = tid >> 6;
  const int wr = w >> 1, wc = w & 1;
  const int quad = lane >> 4, l16 = lane & 15;
  const int m0 = blockIdx.y * 64, n0 = blockIdx.x * 64;
  const int srow = tid >> 2, scol = (tid & 3) * 16;
  f32x4 acc[2][2];
#pragma unroll
  for (int i = 0; i < 2; ++i)
#pragma unroll
    for (int j = 0; j < 2; ++j) acc[i][j] = (f32x4){0.f, 0.f, 0.f, 0.f};
#pragma unroll
  for (int pair = 0; pair < 2; ++pair) {
    const u16* A = pair ? A2 : A1;
    const u16* Wb_ = pair ? W2b : W1b;
    const float* Wf_ = pair ? W2f : W1f;
    const int lda = pair ? lda2 : lda1;
    const int K = pair ? K2 : K1;
    if (K == 0) continue;
    for (int k0 = 0; k0 < K; k0 += 64) {
      const u16* ap = &A[(long)(m0 + srow) * lda + k0 + scol];
      uint4 av0 = *(const uint4*)ap;
      uint4 av1 = *(const uint4*)(ap + 8);
      uint4 bv0, bv1;
      if (Wb_) {
        const u16* wp = &Wb_[(long)(n0 + srow) * K + k0 + scol];
        bv0 = *(const uint4*)wp;
        bv1 = *(const uint4*)(wp + 8);
      } else {
        const float* wp = &Wf_[(long)(n0 + srow) * K + k0 + scol];
        u16 tv[16];
#pragma unroll
        for (int qq = 0; qq < 16; ++qq) tv[qq] = f2bf(wp[qq]);
        bv0 = ((uint4*)tv)[0];
        bv1 = ((uint4*)tv)[1];
      }
      __syncthreads();
      *(uint4*)&As[srow][scol] = av0;
      *(uint4*)&As[srow][scol + 8] = av1;
      *(uint4*)&Bs[srow][scol] = bv0;
      *(uint4*)&Bs[srow][scol + 8] = bv1;
      __syncthreads();
      bf16x8 af[2][2], bfv[2][2];
#pragma unroll
      for (int kk = 0; kk < 2; ++kk) {
#pragma unroll
        for (int i = 0; i < 2; ++i)
          af[i][kk] = *(const bf16x8*)&As[wr * 32 + i * 16 + l16][kk * 32 + quad * 8];
#pragma unroll
        for (int j = 0; j < 2; ++j)
          bfv[j][kk] = *(const bf16x8*)&Bs[wc * 32 + j * 16 + l16][kk * 32 + quad * 8];
      }
#pragma unroll
      for (int kk = 0; kk < 2; ++kk)
#pragma unroll
        for (int i = 0; i < 2; ++i)
#pragma unroll
          for (int j = 0; j < 2; ++j)
            acc[i][j] = __builtin_amdgcn_mfma_f32_16x16x32_bf16(af[i][kk], bfv[j][kk], acc[i][j], 0, 0, 0);
    }
  }
#pragma unroll
  for (int j = 0; j < 2; ++j) {
    const int n = n0 + wc * 32 + j * 16 + l16;
    float bn = bias ? bias[n] : 0.0f;
    float srn[8];
    if (symS) {
      bn += sbr[n];
#pragma unroll
      for (int qq = 0; qq < 8; ++qq) srn[qq] = Srw[n * 8 + qq];
    }
#pragma unroll
    for (int i = 0; i < 2; ++i) {
#pragma unroll
      for (int r = 0; r < 4; ++r) {
        const int m = m0 + wr * 32 + i * 16 + quad * 4 + r;
        float v = acc[i][j][r] + bn;
        if (symS) {
#pragma unroll
          for (int qq = 0; qq < 8; ++qq) v += symS[(long)m * 128 + qq] * srn[qq];
        }
        if (doTanh) v = fast_tanh(v);
        if (outMode == 0) Cb[(long)m * N + n] = f2bf(v);
        else Cf[(long)m * N + n] = v;
      }
    }
  }
}

extern "C" void kernel_launch(void* const* d_in, const int* in_sizes, int n_in,
                              void* d_out, int out_size, void* d_ws, size_t ws_size,
                              hipStream_t stream) {
  const float* inp = (const float*)d_in[0];
  const float* sym = (const float*)d_in[1];
  const float* Wb  = (const float*)d_in[3];
  const float* bb  = (const float*)d_in[4];
  const float* Wl  = (const float*)d_in[5];
  const float* bl  = (const float*)d_in[6];
  const float* Wr  = (const float*)d_in[7];
  const float* Ws  = (const float*)d_in[8];
  const float* bs  = (const float*)d_in[9];
  const float* Sl  = (const float*)d_in[10];
  const float* sbl = (const float*)d_in[11];
  const float* Sr  = (const float*)d_in[12];
  const float* sbr = (const float*)d_in[13];
  const float* Ss  = (const float*)d_in[14];
  const float* sbs = (const float*)d_in[15];

  const long B = 2048, NB = 64, F = 512, H = 1024;
  const long WE = 524288;
  u16* ws = (u16*)d_ws;
  dim3 blk(256);

  const size_t needNew = ((size_t)5 * WE + (size_t)64 * B * F) * 2;  // ~139.5 MB

  if (ws_size >= needNew) {
    u16* WlB = ws;
    u16* WrB = WlB + WE;
    u16* WsB = WrB + WE;
    u16* SlB = WsB + WE;
    u16* SsB = SlB + WE;
    u16* boxesT = SsB + WE;  // [64][2048][512] bf16

    cvt_bf16<<<WE / 2048, blk, 0, stream>>>(Wl, WlB, (int)WE);
    cvt_bf16<<<WE / 2048, blk, 0, stream>>>(Wr, WrB, (int)WE);
    cvt_bf16<<<WE / 2048, blk, 0, stream>>>(Ws, WsB, (int)WE);
    cvt_bf16<<<WE / 2048, blk, 0, stream>>>(Sl, SlB, (int)WE);
    cvt_bf16<<<WE / 2048, blk, 0, stream>>>(Ss, SsB, (int)WE);
    box_allT<<<B, blk, 0, stream>>>(inp, Wb, bb, boxesT);
    chain_kernel<<<128, blk, 0, stream>>>(boxesT, WlB, WrB, WsB, SlB, SsB,
                                          bl, bs, sbl, sbr, sbs, Sr, sym, (float*)d_out);
  } else {
    // fallback: proven round-3 path
    dim3 gH(16, 32), gP(8, 32);
    const size_t szW = 5 * WE * 2, szBoxes = (size_t)B * NB * F * 2;
    const size_t szH = (size_t)B * H * 2, szAcc = (size_t)B * F * 2;
    const size_t needT2 = szW + szBoxes + szH + szAcc;
    const size_t needT3 = szBoxes + szH + szAcc;
    int tier = (ws_size >= needT2) ? 2 : 3;
    u16 *WlB = nullptr, *WrB = nullptr, *WsB = nullptr, *SlB = nullptr, *SsB = nullptr;
    const float *WlF = Wl, *WrF = Wr, *WsF = Ws, *SlF = Sl, *SsF = Ss;
    u16* p = ws;
    if (tier == 2) {
      WlB = p; WrB = p + WE; WsB = p + 2 * WE; SlB = p + 3 * WE; SsB = p + 4 * WE;
      p += 5 * WE;
      cvt_bf16<<<WE / 2048, blk, 0, stream>>>(Wl, WlB, (int)WE);
      cvt_bf16<<<WE / 2048, blk, 0, stream>>>(Wr, WrB, (int)WE);
      cvt_bf16<<<WE / 2048, blk, 0, stream>>>(Ws, WsB, (int)WE);
      cvt_bf16<<<WE / 2048, blk, 0, stream>>>(Sl, SlB, (int)WE);
      cvt_bf16<<<WE / 2048, blk, 0, stream>>>(Ss, SsB, (int)WE);
      WlF = WrF = WsF = SlF = SsF = nullptr;
    }
    u16* boxes = p;
    p += B * NB * F;
    u16* hBuf = p; p += B * H;
    u16* accBuf = p;
    box_all_v2<<<B, blk, 0, stream>>>(inp, Wb, bb, boxes);
    const u16* curA = boxes + 63 * 512;
    int curLda = (int)(NB * F);
    for (int bp = 62; bp >= 0; --bp) {
      gemm64<<<gH, blk, 0, stream>>>(curA, curLda, WlB, WlF, 512,
                                     boxes + (long)bp * 512, (int)(NB * F), WrB, WrF, 512,
                                     bl, nullptr, nullptr, nullptr, 1, 0, hBuf, nullptr, 1024);
      gemm64<<<gP, blk, 0, stream>>>(hBuf, 1024, WsB, WsF, 1024,
                                     nullptr, 0, nullptr, nullptr, 0,
                                     bs, nullptr, nullptr, nullptr, 1, 0, accBuf, nullptr, 512);
      curA = accBuf; curLda = 512;
    }
    for (int symp = 15; symp >= 0; --symp) {
      gemm64<<<gH, blk, 0, stream>>>(accBuf, 512, SlB, SlF, 512,
                                     nullptr, 0, nullptr, nullptr, 0,
                                     sbl, sym + symp * 8, Sr, sbr, 1, 0, hBuf, nullptr, 1024);
      int om = (symp == 0) ? 1 : 0;
      gemm64<<<gP, blk, 0, stream>>>(hBuf, 1024, SsB, SsF, 1024,
                                     nullptr, 0, nullptr, nullptr, 0,
                                     sbs, nullptr, nullptr, nullptr, 1, om, accBuf, (float*)d_out, 512);
    }
  }
  (void)in_sizes; (void)n_in; (void)out_size;
}

// Round 6
// 7147.474 us; speedup vs baseline: 1.6224x; 1.6224x over previous
//
#include <hip/hip_runtime.h>
#include <cmath>

using u16 = unsigned short;
using u32 = unsigned int;
using bf16x8 = __attribute__((ext_vector_type(8))) __bf16;
using f32x4 = __attribute__((ext_vector_type(4))) float;

__device__ __forceinline__ u16 f2bf(float f) {
  union { float f; u32 i; } x; x.f = f;
  u32 r = x.i + 0x7FFFu + ((x.i >> 16) & 1u);
  return (u16)(r >> 16);
}
__device__ __forceinline__ float bf2f(u16 u) {
  union { u32 i; float f; } x; x.i = (u32)u << 16; return x.f;
}
__device__ __forceinline__ float fast_tanh(float x) {
  float e = __expf(2.0f * x);
  return 1.0f - 2.0f / (e + 1.0f);
}

// ---------------- fp32 -> bf16 bulk convert ----------------
__global__ void cvt_bf16(const float* __restrict__ src, u16* __restrict__ dst, int n) {
  int i = (blockIdx.x * 256 + threadIdx.x) * 8;
  if (i + 8 <= n) {
    float4 a = *(const float4*)(src + i), b = *(const float4*)(src + i + 4);
    u16 t[8] = {f2bf(a.x), f2bf(a.y), f2bf(a.z), f2bf(a.w),
                f2bf(b.x), f2bf(b.y), f2bf(b.z), f2bf(b.w)};
    *(uint4*)(dst + i) = *(uint4*)t;
  }
}

// ---------------- boxesT[i][b][f] = tanh(inp[b][i]@Wb^T + bb) ----------------
__global__ __launch_bounds__(256) void box_allT(const float* __restrict__ inp,
    const float* __restrict__ Wb, const float* __restrict__ bb, u16* __restrict__ boxesT) {
  int b = blockIdx.x, t = threadIdx.x;
  __shared__ float sin_[64][12];
  for (int idx = t; idx < 768; idx += 256) sin_[idx / 12][idx % 12] = inp[(long)b * 768 + idx];
  int f0 = (t & 127) * 4, hf = t >> 7;
  float w[4][12], bz[4];
#pragma unroll
  for (int r = 0; r < 4; ++r) {
    bz[r] = bb[f0 + r];
#pragma unroll
    for (int q = 0; q < 12; ++q) w[r][q] = Wb[(f0 + r) * 12 + q];
  }
  __syncthreads();
  for (int i = hf; i < 64; i += 2) {
    float a[4] = {bz[0], bz[1], bz[2], bz[3]};
#pragma unroll
    for (int q = 0; q < 12; ++q) {
      float x = sin_[i][q];
#pragma unroll
      for (int r = 0; r < 4; ++r) a[r] += x * w[r][q];
    }
    u16 p[4];
#pragma unroll
    for (int r = 0; r < 4; ++r) p[r] = f2bf(fast_tanh(a[r]));
    *(uint2*)&boxesT[((long)i * 2048 + b) * 512 + f0] = *(uint2*)p;
  }
}

// ---------------- whole sequential chain, v3: 512 threads (8 waves), batched B-loads ----------------
// 128 blocks x 16 rows. acc/h/box in LDS; weight B-frags streamed from L2 in 16-deep batches.
__global__ __launch_bounds__(512, 2) void chain_v3(
    const u16* __restrict__ boxesT,
    const u16* __restrict__ Wl, const u16* __restrict__ Wr, const u16* __restrict__ Ws,
    const u16* __restrict__ Sl, const u16* __restrict__ Ss,
    const float* __restrict__ bl, const float* __restrict__ bs,
    const float* __restrict__ sbl, const float* __restrict__ sbr,
    const float* __restrict__ sbs, const float* __restrict__ SrF,
    const float* __restrict__ sym, float* __restrict__ outF) {
  __shared__ u16 sA[16][520];   // acc  (A operand, K=512), +8 pad
  __shared__ u16 sB[16][520];   // box
  __shared__ u16 sH[16][1032];  // h    (A operand, K=1024)
  __shared__ float sSym[16][8];

  const int tid = threadIdx.x, lane = tid & 63, w = tid >> 6;  // w: 0..7
  const int q = lane >> 4, l16 = lane & 15;
  const int m0 = blockIdx.x * 16;
  const int brow = tid >> 5, bcol = (tid & 31) * 16;

  // init acc <- boxesT[63]
  {
    const u16* src = boxesT + ((long)63 * 2048 + m0 + brow) * 512 + bcol;
    *(uint4*)&sA[brow][bcol] = *(const uint4*)src;
    *(uint4*)&sA[brow][bcol + 8] = *(const uint4*)(src + 8);
  }
  __syncthreads();

  for (int t = 0; t < 79; ++t) {
    const bool symPhase = (t >= 63);
    const int bp = 62 - t;

    uint4 bxa, bxb;
    if (!symPhase) {
      const u16* bsrc = boxesT + ((long)bp * 2048 + m0 + brow) * 512 + bcol;
      bxa = *(const uint4*)bsrc;
      bxb = *(const uint4*)(bsrc + 8);
    } else {
      int symp = 15 - (t - 63);
      if (tid < 128) sSym[tid >> 3][tid & 7] =
          sym[((long)(m0 + (tid >> 3)) * 16 + symp) * 8 + (tid & 7)];
      __syncthreads();
    }

    // ---- LEFT pass 1: acc @ {Wl|Sl}^T ;  wave n-strip = 128 (np=4 x 32) ----
    const u16* WL = symPhase ? Sl : Wl;
    bf16x8 Af[16];
#pragma unroll
    for (int s = 0; s < 16; ++s) Af[s] = *(const bf16x8*)&sA[l16][s * 32 + q * 8];
    f32x4 C0[4], C1[4];
#pragma unroll
    for (int np = 0; np < 4; ++np) {
      const int n0 = w * 128 + np * 32;
      C0[np] = (f32x4){0.f, 0.f, 0.f, 0.f};
      C1[np] = (f32x4){0.f, 0.f, 0.f, 0.f};
      const u16* w0 = WL + (long)(n0 + l16) * 512 + q * 8;
      const u16* w1 = w0 + 16 * 512;
#pragma unroll
      for (int half = 0; half < 2; ++half) {
        bf16x8 bv0[8], bv1[8];
#pragma unroll
        for (int j = 0; j < 8; ++j) {
          const int s = half * 8 + j;
          bv0[j] = *(const bf16x8*)(w0 + s * 32);
          bv1[j] = *(const bf16x8*)(w1 + s * 32);
        }
#pragma unroll
        for (int j = 0; j < 8; ++j) {
          C0[np] = __builtin_amdgcn_mfma_f32_16x16x32_bf16(Af[half * 8 + j], bv0[j], C0[np], 0, 0, 0);
          C1[np] = __builtin_amdgcn_mfma_f32_16x16x32_bf16(Af[half * 8 + j], bv1[j], C1[np], 0, 0, 0);
        }
      }
    }

    // ---- LEFT pass 2 (chain only): + box_bp @ Wr^T ----
    if (!symPhase) {
      *(uint4*)&sB[brow][bcol] = bxa;
      *(uint4*)&sB[brow][bcol + 8] = bxb;
      __syncthreads();
      bf16x8 Ab[16];
#pragma unroll
      for (int s = 0; s < 16; ++s) Ab[s] = *(const bf16x8*)&sB[l16][s * 32 + q * 8];
#pragma unroll
      for (int np = 0; np < 4; ++np) {
        const int n0 = w * 128 + np * 32;
        const u16* w0 = Wr + (long)(n0 + l16) * 512 + q * 8;
        const u16* w1 = w0 + 16 * 512;
#pragma unroll
        for (int half = 0; half < 2; ++half) {
          bf16x8 bv0[8], bv1[8];
#pragma unroll
          for (int j = 0; j < 8; ++j) {
            const int s = half * 8 + j;
            bv0[j] = *(const bf16x8*)(w0 + s * 32);
            bv1[j] = *(const bf16x8*)(w1 + s * 32);
          }
#pragma unroll
          for (int j = 0; j < 8; ++j) {
            C0[np] = __builtin_amdgcn_mfma_f32_16x16x32_bf16(Ab[half * 8 + j], bv0[j], C0[np], 0, 0, 0);
            C1[np] = __builtin_amdgcn_mfma_f32_16x16x32_bf16(Ab[half * 8 + j], bv1[j], C1[np], 0, 0, 0);
          }
        }
      }
    }

    // ---- LEFT epilogue: bias (+ sym@Sr^T), tanh, write h ----
    float symv[4][8];
    if (symPhase) {
#pragma unroll
      for (int r = 0; r < 4; ++r)
#pragma unroll
        for (int k = 0; k < 8; ++k) symv[r][k] = sSym[q * 4 + r][k];
    }
#pragma unroll
    for (int np = 0; np < 4; ++np) {
      const int n0 = w * 128 + np * 32;
      const int n0b = n0 + l16, n1b = n0 + 16 + l16;
      float bn0, bn1, sr0[8], sr1[8];
      if (!symPhase) { bn0 = bl[n0b]; bn1 = bl[n1b]; }
      else {
        bn0 = sbl[n0b] + sbr[n0b]; bn1 = sbl[n1b] + sbr[n1b];
        *(float4*)&sr0[0] = *(const float4*)&SrF[(long)n0b * 8];
        *(float4*)&sr0[4] = *(const float4*)&SrF[(long)n0b * 8 + 4];
        *(float4*)&sr1[0] = *(const float4*)&SrF[(long)n1b * 8];
        *(float4*)&sr1[4] = *(const float4*)&SrF[(long)n1b * 8 + 4];
      }
#pragma unroll
      for (int r = 0; r < 4; ++r) {
        const int m = q * 4 + r;
        float v0 = C0[np][r] + bn0;
        float v1 = C1[np][r] + bn1;
        if (symPhase) {
#pragma unroll
          for (int k = 0; k < 8; ++k) { v0 += symv[r][k] * sr0[k]; v1 += symv[r][k] * sr1[k]; }
        }
        sH[m][n0b] = f2bf(fast_tanh(v0));
        sH[m][n1b] = f2bf(fast_tanh(v1));
      }
    }
    __syncthreads();

    // ---- PROJ: acc' = tanh(h @ {Ws|Ss}^T + bias) ; wave f-strip = 64 (fp=2 x 32) ----
    const u16* WP = symPhase ? Ss : Ws;
    const float* b2 = symPhase ? sbs : bs;
    f32x4 D0[2], D1[2];
#pragma unroll
    for (int fp = 0; fp < 2; ++fp) {
      D0[fp] = (f32x4){0.f, 0.f, 0.f, 0.f};
      D1[fp] = (f32x4){0.f, 0.f, 0.f, 0.f};
    }
#pragma unroll
    for (int kh = 0; kh < 2; ++kh) {
      bf16x8 Hf[16];
#pragma unroll
      for (int s = 0; s < 16; ++s)
        Hf[s] = *(const bf16x8*)&sH[l16][(kh * 16 + s) * 32 + q * 8];
#pragma unroll
      for (int fp = 0; fp < 2; ++fp) {
        const int f0 = w * 64 + fp * 32;
        const u16* w0 = WP + (long)(f0 + l16) * 1024 + kh * 512 + q * 8;
        const u16* w1 = w0 + 16 * 1024;
#pragma unroll
        for (int half = 0; half < 2; ++half) {
          bf16x8 bv0[8], bv1[8];
#pragma unroll
          for (int j = 0; j < 8; ++j) {
            const int s = half * 8 + j;
            bv0[j] = *(const bf16x8*)(w0 + s * 32);
            bv1[j] = *(const bf16x8*)(w1 + s * 32);
          }
#pragma unroll
          for (int j = 0; j < 8; ++j) {
            D0[fp] = __builtin_amdgcn_mfma_f32_16x16x32_bf16(Hf[half * 8 + j], bv0[j], D0[fp], 0, 0, 0);
            D1[fp] = __builtin_amdgcn_mfma_f32_16x16x32_bf16(Hf[half * 8 + j], bv1[j], D1[fp], 0, 0, 0);
          }
        }
      }
    }
    const bool last = (t == 78);
#pragma unroll
    for (int fp = 0; fp < 2; ++fp) {
      const int f0 = w * 64 + fp * 32;
      const int f0b = f0 + l16, f1b = f0 + 16 + l16;
      float bn0 = b2[f0b], bn1 = b2[f1b];
#pragma unroll
      for (int r = 0; r < 4; ++r) {
        const int m = q * 4 + r;
        float a0 = fast_tanh(D0[fp][r] + bn0);
        float a1 = fast_tanh(D1[fp][r] + bn1);
        sA[m][f0b] = f2bf(a0);
        sA[m][f1b] = f2bf(a1);
        if (last) {
          outF[(long)(m0 + m) * 512 + f0b] = a0;
          outF[(long)(m0 + m) * 512 + f1b] = a1;
        }
      }
    }
    __syncthreads();
  }
}

// ================= fallback kernels (small-ws path, proven round-3/4 logic) =================
__global__ __launch_bounds__(256) void box_all_v2(const float* __restrict__ inp,
    const float* __restrict__ Wb, const float* __restrict__ bb, u16* __restrict__ boxes) {
  int b = blockIdx.x, t = threadIdx.x;
  __shared__ float sin_[64][12];
  for (int idx = t; idx < 768; idx += 256) sin_[idx / 12][idx % 12] = inp[(long)b * 768 + idx];
  const int f0 = t * 2;
  float w0[12], w1[12];
#pragma unroll
  for (int q = 0; q < 12; ++q) { w0[q] = Wb[f0 * 12 + q]; w1[q] = Wb[(f0 + 1) * 12 + q]; }
  float b0 = bb[f0], b1 = bb[f0 + 1];
  __syncthreads();
  for (int i = 0; i < 64; ++i) {
    float a0 = b0, a1 = b1;
#pragma unroll
    for (int q = 0; q < 12; ++q) { float x = sin_[i][q]; a0 += x * w0[q]; a1 += x * w1[q]; }
    u32 pk = (u32)f2bf(fast_tanh(a0)) | ((u32)f2bf(fast_tanh(a1)) << 16);
    *(u32*)&boxes[(((long)b * 64 + i) * 512) + f0] = pk;
  }
}

__global__ __launch_bounds__(256) void gemm64(
    const u16* __restrict__ A1, int lda1,
    const u16* __restrict__ W1b, const float* __restrict__ W1f, int K1,
    const u16* __restrict__ A2, int lda2,
    const u16* __restrict__ W2b, const float* __restrict__ W2f, int K2,
    const float* __restrict__ bias,
    const float* __restrict__ symS, const float* __restrict__ Srw, const float* __restrict__ sbr,
    int doTanh, int outMode,
    u16* __restrict__ Cb, float* __restrict__ Cf, int N) {
  __shared__ u16 As[64][72];
  __shared__ u16 Bs[64][72];
  const int tid = threadIdx.x;
  const int lane = tid & 63, w = tid >> 6;
  const int wr = w >> 1, wc = w & 1;
  const int quad = lane >> 4, l16 = lane & 15;
  const int m0 = blockIdx.y * 64, n0 = blockIdx.x * 64;
  const int srow = tid >> 2, scol = (tid & 3) * 16;
  f32x4 acc[2][2];
#pragma unroll
  for (int i = 0; i < 2; ++i)
#pragma unroll
    for (int j = 0; j < 2; ++j) acc[i][j] = (f32x4){0.f, 0.f, 0.f, 0.f};
#pragma unroll
  for (int pair = 0; pair < 2; ++pair) {
    const u16* A = pair ? A2 : A1;
    const u16* Wb_ = pair ? W2b : W1b;
    const float* Wf_ = pair ? W2f : W1f;
    const int lda = pair ? lda2 : lda1;
    const int K = pair ? K2 : K1;
    if (K == 0) continue;
    for (int k0 = 0; k0 < K; k0 += 64) {
      const u16* ap = &A[(long)(m0 + srow) * lda + k0 + scol];
      uint4 av0 = *(const uint4*)ap;
      uint4 av1 = *(const uint4*)(ap + 8);
      uint4 bv0, bv1;
      if (Wb_) {
        const u16* wp = &Wb_[(long)(n0 + srow) * K + k0 + scol];
        bv0 = *(const uint4*)wp;
        bv1 = *(const uint4*)(wp + 8);
      } else {
        const float* wp = &Wf_[(long)(n0 + srow) * K + k0 + scol];
        u16 tv[16];
#pragma unroll
        for (int qq = 0; qq < 16; ++qq) tv[qq] = f2bf(wp[qq]);
        bv0 = ((uint4*)tv)[0];
        bv1 = ((uint4*)tv)[1];
      }
      __syncthreads();
      *(uint4*)&As[srow][scol] = av0;
      *(uint4*)&As[srow][scol + 8] = av1;
      *(uint4*)&Bs[srow][scol] = bv0;
      *(uint4*)&Bs[srow][scol + 8] = bv1;
      __syncthreads();
      bf16x8 af[2][2], bfv[2][2];
#pragma unroll
      for (int kk = 0; kk < 2; ++kk) {
#pragma unroll
        for (int i = 0; i < 2; ++i)
          af[i][kk] = *(const bf16x8*)&As[wr * 32 + i * 16 + l16][kk * 32 + quad * 8];
#pragma unroll
        for (int j = 0; j < 2; ++j)
          bfv[j][kk] = *(const bf16x8*)&Bs[wc * 32 + j * 16 + l16][kk * 32 + quad * 8];
      }
#pragma unroll
      for (int kk = 0; kk < 2; ++kk)
#pragma unroll
        for (int i = 0; i < 2; ++i)
#pragma unroll
          for (int j = 0; j < 2; ++j)
            acc[i][j] = __builtin_amdgcn_mfma_f32_16x16x32_bf16(af[i][kk], bfv[j][kk], acc[i][j], 0, 0, 0);
    }
  }
#pragma unroll
  for (int j = 0; j < 2; ++j) {
    const int n = n0 + wc * 32 + j * 16 + l16;
    float bn = bias ? bias[n] : 0.0f;
    float srn[8];
    if (symS) {
      bn += sbr[n];
#pragma unroll
      for (int qq = 0; qq < 8; ++qq) srn[qq] = Srw[n * 8 + qq];
    }
#pragma unroll
    for (int i = 0; i < 2; ++i) {
#pragma unroll
      for (int r = 0; r < 4; ++r) {
        const int m = m0 + wr * 32 + i * 16 + quad * 4 + r;
        float v = acc[i][j][r] + bn;
        if (symS) {
#pragma unroll
          for (int qq = 0; qq < 8; ++qq) v += symS[(long)m * 128 + qq] * srn[qq];
        }
        if (doTanh) v = fast_tanh(v);
        if (outMode == 0) Cb[(long)m * N + n] = f2bf(v);
        else Cf[(long)m * N + n] = v;
      }
    }
  }
}

extern "C" void kernel_launch(void* const* d_in, const int* in_sizes, int n_in,
                              void* d_out, int out_size, void* d_ws, size_t ws_size,
                              hipStream_t stream) {
  const float* inp = (const float*)d_in[0];
  const float* sym = (const float*)d_in[1];
  const float* Wb  = (const float*)d_in[3];
  const float* bb  = (const float*)d_in[4];
  const float* Wl  = (const float*)d_in[5];
  const float* bl  = (const float*)d_in[6];
  const float* Wr  = (const float*)d_in[7];
  const float* Ws  = (const float*)d_in[8];
  const float* bs  = (const float*)d_in[9];
  const float* Sl  = (const float*)d_in[10];
  const float* sbl = (const float*)d_in[11];
  const float* Sr  = (const float*)d_in[12];
  const float* sbr = (const float*)d_in[13];
  const float* Ss  = (const float*)d_in[14];
  const float* sbs = (const float*)d_in[15];

  const long B = 2048, NB = 64, F = 512, H = 1024;
  const long WE = 524288;
  u16* ws = (u16*)d_ws;
  dim3 blk(256);

  const size_t needNew = ((size_t)5 * WE + (size_t)64 * B * F) * 2;  // ~139.5 MB

  if (ws_size >= needNew) {
    u16* WlB = ws;
    u16* WrB = WlB + WE;
    u16* WsB = WrB + WE;
    u16* SlB = WsB + WE;
    u16* SsB = SlB + WE;
    u16* boxesT = SsB + WE;  // [64][2048][512] bf16

    cvt_bf16<<<WE / 2048, blk, 0, stream>>>(Wl, WlB, (int)WE);
    cvt_bf16<<<WE / 2048, blk, 0, stream>>>(Wr, WrB, (int)WE);
    cvt_bf16<<<WE / 2048, blk, 0, stream>>>(Ws, WsB, (int)WE);
    cvt_bf16<<<WE / 2048, blk, 0, stream>>>(Sl, SlB, (int)WE);
    cvt_bf16<<<WE / 2048, blk, 0, stream>>>(Ss, SsB, (int)WE);
    box_allT<<<B, blk, 0, stream>>>(inp, Wb, bb, boxesT);
    chain_v3<<<128, dim3(512), 0, stream>>>(boxesT, WlB, WrB, WsB, SlB, SsB,
                                            bl, bs, sbl, sbr, sbs, Sr, sym, (float*)d_out);
  } else {
    // fallback: proven round-3/4 path
    dim3 gH(16, 32), gP(8, 32);
    const size_t szW = 5 * WE * 2, szBoxes = (size_t)B * NB * F * 2;
    const size_t szH = (size_t)B * H * 2, szAcc = (size_t)B * F * 2;
    const size_t needT2 = szW + szBoxes + szH + szAcc;
    int tier = (ws_size >= needT2) ? 2 : 3;
    u16 *WlB = nullptr, *WrB = nullptr, *WsB = nullptr, *SlB = nullptr, *SsB = nullptr;
    const float *WlF = Wl, *WrF = Wr, *WsF = Ws, *SlF = Sl, *SsF = Ss;
    u16* p = ws;
    if (tier == 2) {
      WlB = p; WrB = p + WE; WsB = p + 2 * WE; SlB = p + 3 * WE; SsB = p + 4 * WE;
      p += 5 * WE;
      cvt_bf16<<<WE / 2048, blk, 0, stream>>>(Wl, WlB, (int)WE);
      cvt_bf16<<<WE / 2048, blk, 0, stream>>>(Wr, WrB, (int)WE);
      cvt_bf16<<<WE / 2048, blk, 0, stream>>>(Ws, WsB, (int)WE);
      cvt_bf16<<<WE / 2048, blk, 0, stream>>>(Sl, SlB, (int)WE);
      cvt_bf16<<<WE / 2048, blk, 0, stream>>>(Ss, SsB, (int)WE);
      WlF = WrF = WsF = SlF = SsF = nullptr;
    }
    u16* boxes = p;
    p += B * NB * F;
    u16* hBuf = p; p += B * H;
    u16* accBuf = p;
    box_all_v2<<<B, blk, 0, stream>>>(inp, Wb, bb, boxes);
    const u16* curA = boxes + 63 * 512;
    int curLda = (int)(NB * F);
    for (int bp = 62; bp >= 0; --bp) {
      gemm64<<<gH, blk, 0, stream>>>(curA, curLda, WlB, WlF, 512,
                                     boxes + (long)bp * 512, (int)(NB * F), WrB, WrF, 512,
                                     bl, nullptr, nullptr, nullptr, 1, 0, hBuf, nullptr, 1024);
      gemm64<<<gP, blk, 0, stream>>>(hBuf, 1024, WsB, WsF, 1024,
                                     nullptr, 0, nullptr, nullptr, 0,
                                     bs, nullptr, nullptr, nullptr, 1, 0, accBuf, nullptr, 512);
      curA = accBuf; curLda = 512;
    }
    for (int symp = 15; symp >= 0; --symp) {
      gemm64<<<gH, blk, 0, stream>>>(accBuf, 512, SlB, SlF, 512,
                                     nullptr, 0, nullptr, nullptr, 0,
                                     sbl, sym + symp * 8, Sr, sbr, 1, 0, hBuf, nullptr, 1024);
      int om = (symp == 0) ? 1 : 0;
      gemm64<<<gP, blk, 0, stream>>>(hBuf, 1024, SsB, SsF, 1024,
                                     nullptr, 0, nullptr, nullptr, 0,
                                     sbs, nullptr, nullptr, nullptr, 1, om, accBuf, (float*)d_out, 512);
    }
  }
  (void)in_sizes; (void)n_in; (void)out_size;
}